// Round 3
// baseline (304.455 us; speedup 1.0000x reference)
//
#include <hip/hip_runtime.h>

#define DD 1024   // hidden size
#define MM 256    // random features
#define NN 16384  // hidden states
#define KK 8192   // weight rows

typedef float f32x4 __attribute__((ext_vector_type(4)));
typedef unsigned int u32x4 __attribute__((ext_vector_type(4)));
typedef __bf16 bf16x8 __attribute__((ext_vector_type(8)));
typedef unsigned short u16;
typedef unsigned int u32;

static __device__ __forceinline__ u16 f2bf(float f) {
    u32 u = __builtin_bit_cast(u32, f);
    u32 r = u + 0x7fffu + ((u >> 16) & 1u);
    return (u16)(r >> 16);
}
static __device__ __forceinline__ float bf2f(u16 h) {
    u32 u = ((u32)h) << 16;
    return __builtin_bit_cast(float, u);
}

static __device__ __forceinline__ void gload_lds16(const void* g, void* l) {
    __builtin_amdgcn_global_load_lds(
        (const __attribute__((address_space(1))) u32*)g,
        (__attribute__((address_space(3))) u32*)l, 16, 0, 0);
}

static __device__ __forceinline__ bf16x8 ldfrag(const u16* p) {
    return __builtin_bit_cast(bf16x8, *(const u32x4*)p);
}

#define MFMA16(a, b, c) __builtin_amdgcn_mfma_f32_16x16x32_bf16((a), (b), (c), 0, 0, 0)

// ---------------------------------------------------------------------------
// Kernel 1: omega fp32 -> (hi, lo) bf16 split
// ---------------------------------------------------------------------------
__global__ void k_conv(const float* __restrict__ om, u16* __restrict__ oh,
                       u16* __restrict__ ol) {
    int i = (blockIdx.x * blockDim.x + threadIdx.x) * 4;
    f32x4 x = *(const f32x4*)(om + i);
    ushort4 h, l;
    u16 t;
    t = f2bf(x.x); h.x = t; l.x = f2bf(x.x - bf2f(t));
    t = f2bf(x.y); h.y = t; l.y = f2bf(x.y - bf2f(t));
    t = f2bf(x.z); h.z = t; l.z = f2bf(x.z - bf2f(t));
    t = f2bf(x.w); h.w = t; l.w = f2bf(x.w - bf2f(t));
    *(ushort4*)(oh + i) = h;
    *(ushort4*)(ol + i) = l;
}

// ---------------------------------------------------------------------------
// Kernel 2: Stage A — proj = X @ Omega^T with split-bf16 (3 MFMA products),
// block computes 64 rows x all 256 cols -> rowmax block-local -> phi (bf16)
// ---------------------------------------------------------------------------
__global__ __launch_bounds__(256, 2)
void k_stageA(const float* __restrict__ X,
              const u16* __restrict__ Oh, const u16* __restrict__ Ol,
              u16* __restrict__ phi, float* __restrict__ mx)
{
    __shared__ alignas(16) u16 Ah[64 * 32];
    __shared__ alignas(16) u16 Al[64 * 32];
    __shared__ alignas(16) u16 Bh[256 * 32];
    __shared__ alignas(16) u16 Bl[256 * 32];
    __shared__ float redmax[4][64];

    const int tid  = threadIdx.x;
    const int lane = tid & 63;
    const int wid  = tid >> 6;
    const int row0 = blockIdx.x * 64;

    f32x4 acc[4][4];
#pragma unroll
    for (int m = 0; m < 4; ++m)
#pragma unroll
        for (int n = 0; n < 4; ++n) acc[m][n] = f32x4{0.f, 0.f, 0.f, 0.f};

    // A staging constants (reg-staged fp32 -> hi/lo bf16)
    const int arow  = tid >> 2;          // 0..63
    const int acol8 = (tid & 3) * 8;     // 0,8,16,24
    const float* __restrict__ xrow = X + (long)(row0 + arow) * DD;
    const int a_swz = arow * 32 + ((((acol8 << 1)) ^ (((arow >> 1) & 3) << 4)) >> 1);

    // fragment read offsets (u16 units), swizzle = ((row>>1)&3)<<4 on bytes
    const int r16 = lane & 15;
    const int h8  = (lane >> 4) << 3;
    int aoffs[4], boffs[4];
#pragma unroll
    for (int m = 0; m < 4; ++m) {
        int row = m * 16 + r16;
        aoffs[m] = row * 32 + ((((h8 << 1)) ^ (((row >> 1) & 3) << 4)) >> 1);
    }
#pragma unroll
    for (int n = 0; n < 4; ++n) {
        int row = wid * 64 + n * 16 + r16;
        boffs[n] = row * 32 + ((((h8 << 1)) ^ (((row >> 1) & 3) << 4)) >> 1);
    }

    for (int ks = 0; ks < DD / 32; ++ks) {
        const int k0 = ks * 32;
        // Omega tile hi/lo via async global->LDS (width 16)
#pragma unroll
        for (int s = 0; s < 4; ++s) {
            const int c    = s * 256 + tid;
            const int brow = c >> 2;
            const int cbl  = ((c & 3) << 4) ^ (((brow >> 1) & 3) << 4);
            const int scol = k0 + (cbl >> 1);
            gload_lds16(Oh + brow * DD + scol, Bh + (s * 256 + wid * 64) * 8);
            gload_lds16(Ol + brow * DD + scol, Bl + (s * 256 + wid * 64) * 8);
        }
        // X tile: load fp32, split to hi/lo bf16, write LDS
        f32x4 x0 = *(const f32x4*)(xrow + k0 + acol8);
        f32x4 x1 = *(const f32x4*)(xrow + k0 + acol8 + 4);
        float xs[8];
#pragma unroll
        for (int j = 0; j < 4; ++j) { xs[j] = x0[j]; xs[4 + j] = x1[j]; }
        u32x4 ph, pl;
#pragma unroll
        for (int j = 0; j < 4; ++j) {
            u16 h0 = f2bf(xs[2 * j]);
            u16 h1 = f2bf(xs[2 * j + 1]);
            u16 l0 = f2bf(xs[2 * j] - bf2f(h0));
            u16 l1 = f2bf(xs[2 * j + 1] - bf2f(h1));
            ph[j] = (u32)h0 | ((u32)h1 << 16);
            pl[j] = (u32)l0 | ((u32)l1 << 16);
        }
        *(u32x4*)(Ah + a_swz) = ph;
        *(u32x4*)(Al + a_swz) = pl;
        __syncthreads();

        bf16x8 fah[4], fal[4], fbh[4], fbl[4];
#pragma unroll
        for (int m = 0; m < 4; ++m) {
            fah[m] = ldfrag(Ah + aoffs[m]);
            fal[m] = ldfrag(Al + aoffs[m]);
        }
#pragma unroll
        for (int n = 0; n < 4; ++n) {
            fbh[n] = ldfrag(Bh + boffs[n]);
            fbl[n] = ldfrag(Bl + boffs[n]);
        }
#pragma unroll
        for (int m = 0; m < 4; ++m)
#pragma unroll
            for (int n = 0; n < 4; ++n) {
                acc[m][n] = MFMA16(fah[m], fbh[n], acc[m][n]);
                acc[m][n] = MFMA16(fah[m], fbl[n], acc[m][n]);
                acc[m][n] = MFMA16(fal[m], fbh[n], acc[m][n]);
            }
        __syncthreads();
    }

    // row max: lane-local over n, then across the 16 lanes sharing a row
#pragma unroll
    for (int m = 0; m < 4; ++m) {
#pragma unroll
        for (int i = 0; i < 4; ++i) {
            float v = fmaxf(fmaxf(acc[m][0][i], acc[m][1][i]),
                            fmaxf(acc[m][2][i], acc[m][3][i]));
            v = fmaxf(v, __shfl_xor(v, 1));
            v = fmaxf(v, __shfl_xor(v, 2));
            v = fmaxf(v, __shfl_xor(v, 4));
            v = fmaxf(v, __shfl_xor(v, 8));
            if (r16 == 0) redmax[wid][m * 16 + ((lane >> 4) << 2) + i] = v;
        }
    }
    __syncthreads();
    if (tid < 64) {
        float fm = fmaxf(fmaxf(redmax[0][tid], redmax[1][tid]),
                         fmaxf(redmax[2][tid], redmax[3][tid]));
        mx[row0 + tid] = fm;
    }
#pragma unroll
    for (int m = 0; m < 4; ++m) {
#pragma unroll
        for (int i = 0; i < 4; ++i) {
            const int rl = m * 16 + ((lane >> 4) << 2) + i;
            const float fm = fmaxf(fmaxf(redmax[0][rl], redmax[1][rl]),
                                   fmaxf(redmax[2][rl], redmax[3][rl]));
#pragma unroll
            for (int n = 0; n < 4; ++n) {
                float p  = acc[m][n][i];
                float ph_ = (__expf(p - fm) + 1e-6f) * 0.0625f;
                phi[(long)(row0 + rl) * MM + wid * 64 + n * 16 + r16] = f2bf(ph_);
            }
        }
    }
}

// ---------------------------------------------------------------------------
// Kernel 3: Stage B — rf = phi_h @ phi_w^T (K=256), fused sigmoid epilogue
// 128x128 tile, 4 waves (64x64 each), BK=64
// ---------------------------------------------------------------------------
__global__ __launch_bounds__(256, 2)
void k_stageB(const u16* __restrict__ PH, const u16* __restrict__ PW,
              const float* __restrict__ MH, const float* __restrict__ MW,
              float* __restrict__ out)
{
    __shared__ alignas(16) u16 As[128 * 64];
    __shared__ alignas(16) u16 Bs[128 * 64];

    const int tid  = threadIdx.x;
    const int lane = tid & 63;
    const int wid  = tid >> 6;
    const int bm   = blockIdx.x >> 6;   // 0..127
    const int bn   = blockIdx.x & 63;   // 0..63
    const int row0 = bm * 128, col0 = bn * 128;
    const int wr   = wid >> 1, wc = wid & 1;
    const int r16  = lane & 15;
    const int h8   = (lane >> 4) << 3;

    f32x4 acc[4][4];
#pragma unroll
    for (int m = 0; m < 4; ++m)
#pragma unroll
        for (int n = 0; n < 4; ++n) acc[m][n] = f32x4{0.f, 0.f, 0.f, 0.f};

    // fragment offsets (u16 units) for both 32-wide k-slices; 128B rows,
    // byte swizzle = ((row&7)<<4)
    int aoffs[2][4], boffs[2][4];
#pragma unroll
    for (int sl = 0; sl < 2; ++sl) {
#pragma unroll
        for (int m = 0; m < 4; ++m) {
            int row = wr * 64 + m * 16 + r16;
            aoffs[sl][m] = row * 64 + (((((sl * 32 + h8) << 1)) ^ ((row & 7) << 4)) >> 1);
        }
#pragma unroll
        for (int n = 0; n < 4; ++n) {
            int row = wc * 64 + n * 16 + r16;
            boffs[sl][n] = row * 64 + (((((sl * 32 + h8) << 1)) ^ ((row & 7) << 4)) >> 1);
        }
    }

    for (int ks = 0; ks < 4; ++ks) {
        const int k0 = ks * 64;
#pragma unroll
        for (int s = 0; s < 4; ++s) {
            const int c    = s * 256 + tid;
            const int row  = c >> 3;
            const int cbl  = ((c & 7) << 4) ^ ((row & 7) << 4);
            const int scol = k0 + (cbl >> 1);
            gload_lds16(PH + (long)(row0 + row) * MM + scol, As + (s * 256 + wid * 64) * 8);
            gload_lds16(PW + (long)(col0 + row) * MM + scol, Bs + (s * 256 + wid * 64) * 8);
        }
        __syncthreads();
#pragma unroll
        for (int sl = 0; sl < 2; ++sl) {
            bf16x8 fa[4], fb[4];
#pragma unroll
            for (int m = 0; m < 4; ++m) fa[m] = ldfrag(As + aoffs[sl][m]);
#pragma unroll
            for (int n = 0; n < 4; ++n) fb[n] = ldfrag(Bs + boffs[sl][n]);
#pragma unroll
            for (int m = 0; m < 4; ++m)
#pragma unroll
                for (int n = 0; n < 4; ++n)
                    acc[m][n] = MFMA16(fa[m], fb[n], acc[m][n]);
        }
        __syncthreads();
    }

    // epilogue: logit = clip(log(rf+1e-10) + clip(mh+mw,±80),±80); sigmoid
    float corrw[4];
#pragma unroll
    for (int n = 0; n < 4; ++n) corrw[n] = MW[col0 + wc * 64 + n * 16 + r16];

#pragma unroll
    for (int m = 0; m < 4; ++m) {
#pragma unroll
        for (int i = 0; i < 4; ++i) {
            const int row = row0 + wr * 64 + m * 16 + ((lane >> 4) << 2) + i;
            const float ch = MH[row];
#pragma unroll
            for (int n = 0; n < 4; ++n) {
                float rf   = acc[m][n][i];
                float corr = fminf(fmaxf(ch + corrw[n], -80.f), 80.f);
                float lg   = __logf(rf + 1e-10f) + corr;
                lg = fminf(fmaxf(lg, -80.f), 80.f);
                float o = 1.0f / (1.0f + __expf(-lg));
                out[(long)row * KK + col0 + wc * 64 + n * 16 + r16] = o;
            }
        }
    }
}

// ---------------------------------------------------------------------------
extern "C" void kernel_launch(void* const* d_in, const int* in_sizes, int n_in,
                              void* d_out, int out_size, void* d_ws, size_t ws_size,
                              hipStream_t stream) {
    (void)in_sizes; (void)n_in; (void)out_size; (void)ws_size;
    const float* H  = (const float*)d_in[0];
    const float* W  = (const float*)d_in[1];
    const float* Om = (const float*)d_in[2];
    float* out = (float*)d_out;

    char* ws   = (char*)d_ws;
    u16*  phiH = (u16*)ws;                                       // 8 MB
    u16*  phiW = (u16*)(ws + (size_t)NN * MM * 2);               // 4 MB
    float* mh  = (float*)(ws + (size_t)(NN + KK) * MM * 2);      // 64 KB
    float* mw  = mh + NN;                                        // 32 KB
    u16*  oh   = (u16*)(mw + KK);                                // 512 KB
    u16*  ol   = oh + MM * DD;                                   // 512 KB

    k_conv<<<(MM * DD) / 1024, 256, 0, stream>>>(Om, oh, ol);
    k_stageA<<<NN / 64, 256, 0, stream>>>(H, oh, ol, phiH, mh);
    k_stageA<<<KK / 64, 256, 0, stream>>>(W, oh, ol, phiW, mw);
    k_stageB<<<(NN / 128) * (KK / 128), 256, 0, stream>>>(phiH, phiW, mh, mw, out);
}

// Round 4
// 302.568 us; speedup vs baseline: 1.0062x; 1.0062x over previous
//
#include <hip/hip_runtime.h>

#define DD 1024   // hidden size
#define MM 256    // random features
#define NN 16384  // hidden states
#define KK 8192   // weight rows

typedef float f32x4 __attribute__((ext_vector_type(4)));
typedef unsigned int u32x4 __attribute__((ext_vector_type(4)));
typedef __bf16 bf16x8 __attribute__((ext_vector_type(8)));
typedef unsigned short u16;
typedef unsigned int u32;

static __device__ __forceinline__ u16 f2bf(float f) {
    u32 u = __builtin_bit_cast(u32, f);
    u32 r = u + 0x7fffu + ((u >> 16) & 1u);
    return (u16)(r >> 16);
}
static __device__ __forceinline__ float bf2f(u16 h) {
    u32 u = ((u32)h) << 16;
    return __builtin_bit_cast(float, u);
}

static __device__ __forceinline__ void gload_lds16(const void* g, void* l) {
    __builtin_amdgcn_global_load_lds(
        (const __attribute__((address_space(1))) u32*)g,
        (__attribute__((address_space(3))) u32*)l, 16, 0, 0);
}

static __device__ __forceinline__ bf16x8 ldfrag(const u16* p) {
    return __builtin_bit_cast(bf16x8, *(const u32x4*)p);
}

#define MFMA16(a, b, c) __builtin_amdgcn_mfma_f32_16x16x32_bf16((a), (b), (c), 0, 0, 0)

// ---------------------------------------------------------------------------
// Kernel 1: omega fp32 -> (hi, lo) bf16 split
// ---------------------------------------------------------------------------
__global__ void k_conv(const float* __restrict__ om, u16* __restrict__ oh,
                       u16* __restrict__ ol) {
    int i = (blockIdx.x * blockDim.x + threadIdx.x) * 4;
    f32x4 x = *(const f32x4*)(om + i);
    ushort4 h, l;
    u16 t;
    t = f2bf(x.x); h.x = t; l.x = f2bf(x.x - bf2f(t));
    t = f2bf(x.y); h.y = t; l.y = f2bf(x.y - bf2f(t));
    t = f2bf(x.z); h.z = t; l.z = f2bf(x.z - bf2f(t));
    t = f2bf(x.w); h.w = t; l.w = f2bf(x.w - bf2f(t));
    *(ushort4*)(oh + i) = h;
    *(ushort4*)(ol + i) = l;
}

// ---------------------------------------------------------------------------
// Kernel 2: Stage A — proj = X @ Omega^T with split-bf16 (3 MFMA products),
// block computes 64 rows x all 256 cols -> rowmax block-local -> phi (bf16)
// ---------------------------------------------------------------------------
__global__ __launch_bounds__(256, 2)
void k_stageA(const float* __restrict__ X,
              const u16* __restrict__ Oh, const u16* __restrict__ Ol,
              u16* __restrict__ phi, float* __restrict__ mx)
{
    __shared__ alignas(16) u16 Ah[64 * 32];
    __shared__ alignas(16) u16 Al[64 * 32];
    __shared__ alignas(16) u16 Bh[256 * 32];
    __shared__ alignas(16) u16 Bl[256 * 32];
    __shared__ float redmax[4][64];

    const int tid  = threadIdx.x;
    const int lane = tid & 63;
    const int wid  = tid >> 6;
    const int row0 = blockIdx.x * 64;

    f32x4 acc[4][4];
#pragma unroll
    for (int m = 0; m < 4; ++m)
#pragma unroll
        for (int n = 0; n < 4; ++n) acc[m][n] = f32x4{0.f, 0.f, 0.f, 0.f};

    // A staging constants (reg-staged fp32 -> hi/lo bf16)
    const int arow  = tid >> 2;          // 0..63
    const int acol8 = (tid & 3) * 8;     // 0,8,16,24
    const float* __restrict__ xrow = X + (long)(row0 + arow) * DD;
    const int a_swz = arow * 32 + ((((acol8 << 1)) ^ (((arow >> 1) & 3) << 4)) >> 1);

    // fragment read offsets (u16 units), swizzle = ((row>>1)&3)<<4 on bytes
    const int r16 = lane & 15;
    const int h8  = (lane >> 4) << 3;
    int aoffs[4], boffs[4];
#pragma unroll
    for (int m = 0; m < 4; ++m) {
        int row = m * 16 + r16;
        aoffs[m] = row * 32 + ((((h8 << 1)) ^ (((row >> 1) & 3) << 4)) >> 1);
    }
#pragma unroll
    for (int n = 0; n < 4; ++n) {
        int row = wid * 64 + n * 16 + r16;
        boffs[n] = row * 32 + ((((h8 << 1)) ^ (((row >> 1) & 3) << 4)) >> 1);
    }

    for (int ks = 0; ks < DD / 32; ++ks) {
        const int k0 = ks * 32;
        // Omega tile hi/lo via async global->LDS (width 16)
#pragma unroll
        for (int s = 0; s < 4; ++s) {
            const int c    = s * 256 + tid;
            const int brow = c >> 2;
            const int cbl  = ((c & 3) << 4) ^ (((brow >> 1) & 3) << 4);
            const int scol = k0 + (cbl >> 1);
            gload_lds16(Oh + brow * DD + scol, Bh + (s * 256 + wid * 64) * 8);
            gload_lds16(Ol + brow * DD + scol, Bl + (s * 256 + wid * 64) * 8);
        }
        // X tile: load fp32, split to hi/lo bf16, write LDS
        f32x4 x0 = *(const f32x4*)(xrow + k0 + acol8);
        f32x4 x1 = *(const f32x4*)(xrow + k0 + acol8 + 4);
        float xs[8];
#pragma unroll
        for (int j = 0; j < 4; ++j) { xs[j] = x0[j]; xs[4 + j] = x1[j]; }
        u32x4 ph, pl;
#pragma unroll
        for (int j = 0; j < 4; ++j) {
            u16 h0 = f2bf(xs[2 * j]);
            u16 h1 = f2bf(xs[2 * j + 1]);
            u16 l0 = f2bf(xs[2 * j] - bf2f(h0));
            u16 l1 = f2bf(xs[2 * j + 1] - bf2f(h1));
            ph[j] = (u32)h0 | ((u32)h1 << 16);
            pl[j] = (u32)l0 | ((u32)l1 << 16);
        }
        *(u32x4*)(Ah + a_swz) = ph;
        *(u32x4*)(Al + a_swz) = pl;
        __syncthreads();

        bf16x8 fah[4], fal[4], fbh[4], fbl[4];
#pragma unroll
        for (int m = 0; m < 4; ++m) {
            fah[m] = ldfrag(Ah + aoffs[m]);
            fal[m] = ldfrag(Al + aoffs[m]);
        }
#pragma unroll
        for (int n = 0; n < 4; ++n) {
            fbh[n] = ldfrag(Bh + boffs[n]);
            fbl[n] = ldfrag(Bl + boffs[n]);
        }
#pragma unroll
        for (int m = 0; m < 4; ++m)
#pragma unroll
            for (int n = 0; n < 4; ++n) {
                acc[m][n] = MFMA16(fah[m], fbh[n], acc[m][n]);
                acc[m][n] = MFMA16(fah[m], fbl[n], acc[m][n]);
                acc[m][n] = MFMA16(fal[m], fbh[n], acc[m][n]);
            }
        __syncthreads();
    }

    // row max: lane-local over n, then across the 16 lanes sharing a row
#pragma unroll
    for (int m = 0; m < 4; ++m) {
#pragma unroll
        for (int i = 0; i < 4; ++i) {
            float v = fmaxf(fmaxf(acc[m][0][i], acc[m][1][i]),
                            fmaxf(acc[m][2][i], acc[m][3][i]));
            v = fmaxf(v, __shfl_xor(v, 1));
            v = fmaxf(v, __shfl_xor(v, 2));
            v = fmaxf(v, __shfl_xor(v, 4));
            v = fmaxf(v, __shfl_xor(v, 8));
            if (r16 == 0) redmax[wid][m * 16 + ((lane >> 4) << 2) + i] = v;
        }
    }
    __syncthreads();
    if (tid < 64) {
        float fm = fmaxf(fmaxf(redmax[0][tid], redmax[1][tid]),
                         fmaxf(redmax[2][tid], redmax[3][tid]));
        mx[row0 + tid] = fm;
    }
#pragma unroll
    for (int m = 0; m < 4; ++m) {
#pragma unroll
        for (int i = 0; i < 4; ++i) {
            const int rl = m * 16 + ((lane >> 4) << 2) + i;
            const float fm = fmaxf(fmaxf(redmax[0][rl], redmax[1][rl]),
                                   fmaxf(redmax[2][rl], redmax[3][rl]));
#pragma unroll
            for (int n = 0; n < 4; ++n) {
                float p  = acc[m][n][i];
                float ph_ = (__expf(p - fm) + 1e-6f) * 0.0625f;
                phi[(long)(row0 + rl) * MM + wid * 64 + n * 16 + r16] = f2bf(ph_);
            }
        }
    }
}

// ---------------------------------------------------------------------------
// Kernel 3: Stage B — rf = phi_h @ phi_w^T (K=256), fused sigmoid epilogue
// 128x128 tile, 4 waves (64x64 each), BK=64
// ---------------------------------------------------------------------------
__global__ __launch_bounds__(256, 2)
void k_stageB(const u16* __restrict__ PH, const u16* __restrict__ PW,
              const float* __restrict__ MH, const float* __restrict__ MW,
              float* __restrict__ out)
{
    __shared__ alignas(16) u16 As[128 * 64];
    __shared__ alignas(16) u16 Bs[128 * 64];

    const int tid  = threadIdx.x;
    const int lane = tid & 63;
    const int wid  = tid >> 6;
    const int bm   = blockIdx.x >> 6;   // 0..127
    const int bn   = blockIdx.x & 63;   // 0..63
    const int row0 = bm * 128, col0 = bn * 128;
    const int wr   = wid >> 1, wc = wid & 1;
    const int r16  = lane & 15;
    const int h8   = (lane >> 4) << 3;

    f32x4 acc[4][4];
#pragma unroll
    for (int m = 0; m < 4; ++m)
#pragma unroll
        for (int n = 0; n < 4; ++n) acc[m][n] = f32x4{0.f, 0.f, 0.f, 0.f};

    // fragment offsets (u16 units) for both 32-wide k-slices; 128B rows,
    // byte swizzle = ((row&7)<<4)
    int aoffs[2][4], boffs[2][4];
#pragma unroll
    for (int sl = 0; sl < 2; ++sl) {
#pragma unroll
        for (int m = 0; m < 4; ++m) {
            int row = wr * 64 + m * 16 + r16;
            aoffs[sl][m] = row * 64 + (((((sl * 32 + h8) << 1)) ^ ((row & 7) << 4)) >> 1);
        }
#pragma unroll
        for (int n = 0; n < 4; ++n) {
            int row = wc * 64 + n * 16 + r16;
            boffs[sl][n] = row * 64 + (((((sl * 32 + h8) << 1)) ^ ((row & 7) << 4)) >> 1);
        }
    }

    for (int ks = 0; ks < 4; ++ks) {
        const int k0 = ks * 64;
#pragma unroll
        for (int s = 0; s < 4; ++s) {
            const int c    = s * 256 + tid;
            const int row  = c >> 3;
            const int cbl  = ((c & 7) << 4) ^ ((row & 7) << 4);
            const int scol = k0 + (cbl >> 1);
            gload_lds16(PH + (long)(row0 + row) * MM + scol, As + (s * 256 + wid * 64) * 8);
            gload_lds16(PW + (long)(col0 + row) * MM + scol, Bs + (s * 256 + wid * 64) * 8);
        }
        __syncthreads();
#pragma unroll
        for (int sl = 0; sl < 2; ++sl) {
            bf16x8 fa[4], fb[4];
#pragma unroll
            for (int m = 0; m < 4; ++m) fa[m] = ldfrag(As + aoffs[sl][m]);
#pragma unroll
            for (int n = 0; n < 4; ++n) fb[n] = ldfrag(Bs + boffs[sl][n]);
#pragma unroll
            for (int m = 0; m < 4; ++m)
#pragma unroll
                for (int n = 0; n < 4; ++n)
                    acc[m][n] = MFMA16(fa[m], fb[n], acc[m][n]);
        }
        __syncthreads();
    }

    // epilogue: logit = clip(log(rf+1e-10) + clip(mh+mw,±80),±80); sigmoid
    float corrw[4];
#pragma unroll
    for (int n = 0; n < 4; ++n) corrw[n] = MW[col0 + wc * 64 + n * 16 + r16];

#pragma unroll
    for (int m = 0; m < 4; ++m) {
#pragma unroll
        for (int i = 0; i < 4; ++i) {
            const int row = row0 + wr * 64 + m * 16 + ((lane >> 4) << 2) + i;
            const float ch = MH[row];
#pragma unroll
            for (int n = 0; n < 4; ++n) {
                float rf   = acc[m][n][i];
                float corr = fminf(fmaxf(ch + corrw[n], -80.f), 80.f);
                float lg   = __logf(rf + 1e-10f) + corr;
                lg = fminf(fmaxf(lg, -80.f), 80.f);
                float o = 1.0f / (1.0f + __expf(-lg));
                out[(long)row * KK + col0 + wc * 64 + n * 16 + r16] = o;
            }
        }
    }
}

// ---------------------------------------------------------------------------
extern "C" void kernel_launch(void* const* d_in, const int* in_sizes, int n_in,
                              void* d_out, int out_size, void* d_ws, size_t ws_size,
                              hipStream_t stream) {
    (void)in_sizes; (void)n_in; (void)out_size; (void)ws_size;
    const float* H  = (const float*)d_in[0];
    const float* W  = (const float*)d_in[1];
    const float* Om = (const float*)d_in[2];
    float* out = (float*)d_out;

    char* ws   = (char*)d_ws;
    u16*  phiH = (u16*)ws;                                       // 8 MB
    u16*  phiW = (u16*)(ws + (size_t)NN * MM * 2);               // 4 MB
    float* mh  = (float*)(ws + (size_t)(NN + KK) * MM * 2);      // 64 KB
    float* mw  = mh + NN;                                        // 32 KB
    u16*  oh   = (u16*)(mw + KK);                                // 512 KB
    u16*  ol   = oh + MM * DD;                                   // 512 KB

    k_conv<<<(MM * DD) / 1024, 256, 0, stream>>>(Om, oh, ol);
    k_stageA<<<NN / 64, 256, 0, stream>>>(H, oh, ol, phiH, mh);
    k_stageA<<<KK / 64, 256, 0, stream>>>(W, oh, ol, phiW, mw);
    k_stageB<<<(NN / 128) * (KK / 128), 256, 0, stream>>>(phiH, phiW, mh, mw, out);
}

// Round 5
// 196.316 us; speedup vs baseline: 1.5508x; 1.5412x over previous
//
#include <hip/hip_runtime.h>

#define DD 1024   // hidden size
#define MM 256    // random features
#define NN 16384  // hidden states
#define KK 8192   // weight rows

typedef float f32x4 __attribute__((ext_vector_type(4)));
typedef unsigned int u32x4 __attribute__((ext_vector_type(4)));
typedef unsigned int u32x2 __attribute__((ext_vector_type(2)));
typedef __bf16 bf16x8 __attribute__((ext_vector_type(8)));
typedef unsigned short u16;
typedef unsigned int u32;

static __device__ __forceinline__ u16 f2bf(float f) {
    u32 u = __builtin_bit_cast(u32, f);
    u32 r = u + 0x7fffu + ((u >> 16) & 1u);
    return (u16)(r >> 16);
}
static __device__ __forceinline__ float bf2f(u16 h) {
    u32 u = ((u32)h) << 16;
    return __builtin_bit_cast(float, u);
}

static __device__ __forceinline__ void gload_lds16(const void* g, void* l) {
    __builtin_amdgcn_global_load_lds(
        (const __attribute__((address_space(1))) u32*)g,
        (__attribute__((address_space(3))) u32*)l, 16, 0, 0);
}

static __device__ __forceinline__ bf16x8 ldfrag(const u16* p) {
    return __builtin_bit_cast(bf16x8, *(const u32x4*)p);
}

#define MFMA16(a, b, c) __builtin_amdgcn_mfma_f32_16x16x32_bf16((a), (b), (c), 0, 0, 0)

// ---------------------------------------------------------------------------
// Kernel 1: omega fp32 -> (hi, lo) bf16 split
// ---------------------------------------------------------------------------
__global__ void k_conv(const float* __restrict__ om, u16* __restrict__ oh,
                       u16* __restrict__ ol) {
    int i = (blockIdx.x * blockDim.x + threadIdx.x) * 4;
    f32x4 x = *(const f32x4*)(om + i);
    ushort4 h, l;
    u16 t;
    t = f2bf(x.x); h.x = t; l.x = f2bf(x.x - bf2f(t));
    t = f2bf(x.y); h.y = t; l.y = f2bf(x.y - bf2f(t));
    t = f2bf(x.z); h.z = t; l.z = f2bf(x.z - bf2f(t));
    t = f2bf(x.w); h.w = t; l.w = f2bf(x.w - bf2f(t));
    *(ushort4*)(oh + i) = h;
    *(ushort4*)(ol + i) = l;
}

// ---------------------------------------------------------------------------
// Kernel 2: merged Stage A (H and W in one grid) — proj = X @ Omega^T with
// split-bf16 (3 MFMA products). Block = 32 rows x all 256 cols -> rowmax
// block-local -> phi (bf16) + em = exp(clamp(-rowmax, +-87)) (f32).
// 32 rows/block: H=512 blocks + W=256 blocks = 768 -> ~3 blocks/CU TLP.
// ---------------------------------------------------------------------------
__global__ __launch_bounds__(256, 4)
void k_stageA(const float* __restrict__ Hs, const float* __restrict__ Ws,
              const u16* __restrict__ Oh, const u16* __restrict__ Ol,
              u16* __restrict__ phiH, u16* __restrict__ phiW,
              float* __restrict__ emH, float* __restrict__ emW)
{
    __shared__ alignas(16) u16 Ah[32 * 32];
    __shared__ alignas(16) u16 Al[32 * 32];
    __shared__ alignas(16) u16 Bh[256 * 32];
    __shared__ alignas(16) u16 Bl[256 * 32];
    __shared__ float redmax[4][32];

    const int tid  = threadIdx.x;
    const int lane = tid & 63;
    const int wid  = tid >> 6;

    const float* __restrict__ X;
    u16* __restrict__ phi;
    float* __restrict__ em;
    int row0;
    if (blockIdx.x < NN / 32) {
        X = Hs; phi = phiH; em = emH; row0 = blockIdx.x * 32;
    } else {
        X = Ws; phi = phiW; em = emW; row0 = (blockIdx.x - NN / 32) * 32;
    }

    f32x4 acc[2][4];
#pragma unroll
    for (int m = 0; m < 2; ++m)
#pragma unroll
        for (int n = 0; n < 4; ++n) acc[m][n] = f32x4{0.f, 0.f, 0.f, 0.f};

    // A staging: thread loads float4 (row arow, fp32 cols acol..acol+3)
    const int arow = tid >> 3;           // 0..31
    const int acol = (tid & 7) * 4;      // 0,4,..,28
    const float* __restrict__ xrow = X + (long)(row0 + arow) * DD;
    // u16-unit LDS index; XOR swizzle on 8-u16 (16B) blocks
    const int a_idx = arow * 32 + (acol ^ (((arow >> 1) & 3) << 3));

    const int r16 = lane & 15;
    const int h8  = (lane >> 4) << 3;
    int aoffs[2], boffs[4];
#pragma unroll
    for (int m = 0; m < 2; ++m) {
        int row = m * 16 + r16;
        aoffs[m] = row * 32 + (h8 ^ (((row >> 1) & 3) << 3));
    }
#pragma unroll
    for (int n = 0; n < 4; ++n) {
        int row = wid * 64 + n * 16 + r16;
        boffs[n] = row * 32 + (h8 ^ (((row >> 1) & 3) << 3));
    }

    for (int ks = 0; ks < DD / 32; ++ks) {
        const int k0 = ks * 32;
        // Omega tile hi/lo via async global->LDS (width 16), pre-swizzled src
#pragma unroll
        for (int s = 0; s < 4; ++s) {
            const int c    = s * 256 + tid;
            const int brow = c >> 2;
            const int scol = k0 + (((c & 3) << 3) ^ (((brow >> 1) & 3) << 3));
            gload_lds16(Oh + brow * DD + scol, Bh + (s * 256 + wid * 64) * 8);
            gload_lds16(Ol + brow * DD + scol, Bl + (s * 256 + wid * 64) * 8);
        }
        // X tile: load fp32x4, split to hi/lo bf16, write LDS (8B)
        f32x4 x = *(const f32x4*)(xrow + k0 + acol);
        u32x2 ph, pl;
#pragma unroll
        for (int j = 0; j < 2; ++j) {
            u16 h0 = f2bf(x[2 * j]);
            u16 h1 = f2bf(x[2 * j + 1]);
            u16 l0 = f2bf(x[2 * j] - bf2f(h0));
            u16 l1 = f2bf(x[2 * j + 1] - bf2f(h1));
            ph[j] = (u32)h0 | ((u32)h1 << 16);
            pl[j] = (u32)l0 | ((u32)l1 << 16);
        }
        *(u32x2*)(Ah + a_idx) = ph;
        *(u32x2*)(Al + a_idx) = pl;
        __syncthreads();

        bf16x8 fah[2], fal[2], fbh[4], fbl[4];
#pragma unroll
        for (int m = 0; m < 2; ++m) {
            fah[m] = ldfrag(Ah + aoffs[m]);
            fal[m] = ldfrag(Al + aoffs[m]);
        }
#pragma unroll
        for (int n = 0; n < 4; ++n) {
            fbh[n] = ldfrag(Bh + boffs[n]);
            fbl[n] = ldfrag(Bl + boffs[n]);
        }
#pragma unroll
        for (int m = 0; m < 2; ++m)
#pragma unroll
            for (int n = 0; n < 4; ++n) {
                acc[m][n] = MFMA16(fah[m], fbh[n], acc[m][n]);
                acc[m][n] = MFMA16(fah[m], fbl[n], acc[m][n]);
                acc[m][n] = MFMA16(fal[m], fbh[n], acc[m][n]);
            }
        __syncthreads();
    }

    // row max: lane-local over n, then across the 16 lanes sharing a row
#pragma unroll
    for (int m = 0; m < 2; ++m) {
#pragma unroll
        for (int i = 0; i < 4; ++i) {
            float v = fmaxf(fmaxf(acc[m][0][i], acc[m][1][i]),
                            fmaxf(acc[m][2][i], acc[m][3][i]));
            v = fmaxf(v, __shfl_xor(v, 1));
            v = fmaxf(v, __shfl_xor(v, 2));
            v = fmaxf(v, __shfl_xor(v, 4));
            v = fmaxf(v, __shfl_xor(v, 8));
            if (r16 == 0) redmax[wid][m * 16 + ((lane >> 4) << 2) + i] = v;
        }
    }
    __syncthreads();
    if (tid < 32) {
        float fm = fmaxf(fmaxf(redmax[0][tid], redmax[1][tid]),
                         fmaxf(redmax[2][tid], redmax[3][tid]));
        // em = exp(-clamp) so stage B epilogue needs no log/exp
        em[row0 + tid] = __expf(fminf(fmaxf(-fm, -87.f), 87.f));
    }
#pragma unroll
    for (int m = 0; m < 2; ++m) {
#pragma unroll
        for (int i = 0; i < 4; ++i) {
            const int rl = m * 16 + ((lane >> 4) << 2) + i;
            const float fm = fmaxf(fmaxf(redmax[0][rl], redmax[1][rl]),
                                   fmaxf(redmax[2][rl], redmax[3][rl]));
#pragma unroll
            for (int n = 0; n < 4; ++n) {
                float p   = acc[m][n][i];
                float ph_ = (__expf(p - fm) + 1e-6f) * 0.0625f;
                phi[(long)(row0 + rl) * MM + wid * 64 + n * 16 + r16] = f2bf(ph_);
            }
        }
    }
}

// ---------------------------------------------------------------------------
// Kernel 3: Stage B — rf = phi_h @ phi_w^T (K=256), epilogue
//   out = rf' / (rf' + eh*ew),  rf' = rf + 1e-10   (no log/exp/div!)
// 128x128 tile, 4 waves (64x64 each), BK=64, non-temporal output stores.
// ---------------------------------------------------------------------------
__global__ __launch_bounds__(256, 3)
void k_stageB(const u16* __restrict__ PH, const u16* __restrict__ PW,
              const float* __restrict__ EH, const float* __restrict__ EW,
              float* __restrict__ out)
{
    __shared__ alignas(16) u16 As[128 * 64];
    __shared__ alignas(16) u16 Bs[128 * 64];

    const int tid  = threadIdx.x;
    const int lane = tid & 63;
    const int wid  = tid >> 6;
    const int bm   = blockIdx.x >> 6;   // 0..127
    const int bn   = blockIdx.x & 63;   // 0..63
    const int row0 = bm * 128, col0 = bn * 128;
    const int wr   = wid >> 1, wc = wid & 1;
    const int r16  = lane & 15;
    const int h8   = (lane >> 4) << 3;

    f32x4 acc[4][4];
#pragma unroll
    for (int m = 0; m < 4; ++m)
#pragma unroll
        for (int n = 0; n < 4; ++n) acc[m][n] = f32x4{0.f, 0.f, 0.f, 0.f};

    // fragment offsets (u16 units) for both 32-wide k-slices; 128B rows,
    // byte swizzle = ((row&7)<<4)
    int aoffs[2][4], boffs[2][4];
#pragma unroll
    for (int sl = 0; sl < 2; ++sl) {
#pragma unroll
        for (int m = 0; m < 4; ++m) {
            int row = wr * 64 + m * 16 + r16;
            aoffs[sl][m] = row * 64 + (((((sl * 32 + h8) << 1)) ^ ((row & 7) << 4)) >> 1);
        }
#pragma unroll
        for (int n = 0; n < 4; ++n) {
            int row = wc * 64 + n * 16 + r16;
            boffs[sl][n] = row * 64 + (((((sl * 32 + h8) << 1)) ^ ((row & 7) << 4)) >> 1);
        }
    }

    for (int ks = 0; ks < 4; ++ks) {
        const int k0 = ks * 64;
#pragma unroll
        for (int s = 0; s < 4; ++s) {
            const int c    = s * 256 + tid;
            const int row  = c >> 3;
            const int cbl  = ((c & 7) << 4) ^ ((row & 7) << 4);
            const int scol = k0 + (cbl >> 1);
            gload_lds16(PH + (long)(row0 + row) * MM + scol, As + (s * 256 + wid * 64) * 8);
            gload_lds16(PW + (long)(col0 + row) * MM + scol, Bs + (s * 256 + wid * 64) * 8);
        }
        __syncthreads();
#pragma unroll
        for (int sl = 0; sl < 2; ++sl) {
            bf16x8 fa[4], fb[4];
#pragma unroll
            for (int m = 0; m < 4; ++m) fa[m] = ldfrag(As + aoffs[sl][m]);
#pragma unroll
            for (int n = 0; n < 4; ++n) fb[n] = ldfrag(Bs + boffs[sl][n]);
#pragma unroll
            for (int m = 0; m < 4; ++m)
#pragma unroll
                for (int n = 0; n < 4; ++n)
                    acc[m][n] = MFMA16(fa[m], fb[n], acc[m][n]);
        }
        __syncthreads();
    }

    // epilogue: out = rf' / (rf' + eh*ew)
    float ew_[4];
#pragma unroll
    for (int n = 0; n < 4; ++n) ew_[n] = EW[col0 + wc * 64 + n * 16 + r16];

#pragma unroll
    for (int m = 0; m < 4; ++m) {
#pragma unroll
        for (int i = 0; i < 4; ++i) {
            const int row = row0 + wr * 64 + m * 16 + ((lane >> 4) << 2) + i;
            const float eh = EH[row];
#pragma unroll
            for (int n = 0; n < 4; ++n) {
                float rf = acc[m][n][i] + 1e-10f;
                float t  = eh * ew_[n];
                float o  = rf * __builtin_amdgcn_rcpf(rf + t);
                __builtin_nontemporal_store(
                    o, &out[(long)row * KK + col0 + wc * 64 + n * 16 + r16]);
            }
        }
    }
}

// ---------------------------------------------------------------------------
extern "C" void kernel_launch(void* const* d_in, const int* in_sizes, int n_in,
                              void* d_out, int out_size, void* d_ws, size_t ws_size,
                              hipStream_t stream) {
    (void)in_sizes; (void)n_in; (void)out_size; (void)ws_size;
    const float* H  = (const float*)d_in[0];
    const float* W  = (const float*)d_in[1];
    const float* Om = (const float*)d_in[2];
    float* out = (float*)d_out;

    char* ws   = (char*)d_ws;
    u16*  phiH = (u16*)ws;                                       // 8 MB
    u16*  phiW = (u16*)(ws + (size_t)NN * MM * 2);               // 4 MB
    float* emh = (float*)(ws + (size_t)(NN + KK) * MM * 2);      // 64 KB
    float* emw = emh + NN;                                       // 32 KB
    u16*  oh   = (u16*)(emw + KK);                               // 512 KB
    u16*  ol   = oh + MM * DD;                                   // 512 KB

    k_conv<<<(MM * DD) / 1024, 256, 0, stream>>>(Om, oh, ol);
    k_stageA<<<(NN + KK) / 32, 256, 0, stream>>>(H, W, oh, ol, phiH, phiW, emh, emw);
    k_stageB<<<(NN / 128) * (KK / 128), 256, 0, stream>>>(phiH, phiW, emh, emw, out);
}